// Round 1
// baseline (509.992 us; speedup 1.0000x reference)
//
#include <hip/hip_runtime.h>

#define N_NODES 131072
#define C_DIM   128
#define H_DIM   128
#define B_SEG   1024
#define M_TILE  128
#define K_TILE  32
#define CAP     1024

// ---------------------------------------------------------------------------
// Kernel 1: per-node readout  v[n] = lin(n) + relu(x3 @ W1 + b1) @ W2 + b2
// ---------------------------------------------------------------------------
__global__ __launch_bounds__(256, 3)
void node_readout_kernel(const float* __restrict__ emb,
                         const float* __restrict__ W_lins,
                         const float* __restrict__ b_lins,
                         const float* __restrict__ W1,
                         const float* __restrict__ b1,
                         const float* __restrict__ W2,
                         const float* __restrict__ b2,
                         float* __restrict__ v_out)
{
    __shared__ float Yt[K_TILE * M_TILE];     // [cc][m]  16 KB
    __shared__ float W1s[K_TILE * H_DIM];     // [cc][j]  16 KB
    __shared__ float WLs[3 * C_DIM];          // 1.5 KB
    __shared__ float lin_lds[M_TILE];         // 0.5 KB
    __shared__ float nl_red[M_TILE * 17];     // 8.7 KB (pad 17: conflict-free)

    const int t = threadIdx.x;
    const int nbase = blockIdx.x * M_TILE;

    // loader mapping: 2 threads per node
    const int lm = t >> 1;
    const int lq = t & 1;
    // gemm mapping: 16 j-groups x 16 m-groups
    const int jg = t & 15;
    const int mg = t >> 4;

    // stage W_lins once
    for (int i = t; i < 3 * C_DIM; i += 256) WLs[i] = W_lins[i];

    // per-thread j set: j = jg + 16*ji (strided -> broadcast LDS reads)
    float b1r[8], W2r[8];
    #pragma unroll
    for (int ji = 0; ji < 8; ++ji) {
        int j = jg + 16 * ji;
        b1r[ji] = b1[j];
        W2r[ji] = W2[j];
    }

    float acc[8][8];
    #pragma unroll
    for (int mi = 0; mi < 8; ++mi)
        #pragma unroll
        for (int ji = 0; ji < 8; ++ji) acc[mi][ji] = 0.0f;

    float lin = 0.0f;
    const float4* node_ptr =
        (const float4*)(emb + (size_t)(nbase + lm) * (C_DIM * 4));

    __syncthreads();   // WLs ready

    for (int ct = 0; ct < C_DIM / K_TILE; ++ct) {
        if (ct) __syncthreads();   // previous tile fully consumed

        // stage W1 tile: 32 rows x 128 = 16KB contiguous
        {
            const float4* src = (const float4*)(W1 + ct * K_TILE * H_DIM);
            float4* dst = (float4*)W1s;
            #pragma unroll
            for (int i = 0; i < 4; ++i) dst[t + 256 * i] = src[t + 256 * i];
        }
        // load X chunk: 2 threads/node, interleaved c -> 32B-contig per pair
        {
            #pragma unroll
            for (int k = 0; k < 16; ++k) {
                int cc = lq + 2 * k;
                float4 x = node_ptr[ct * K_TILE + cc];
                int c = ct * K_TILE + cc;
                lin += x.x * WLs[c] + x.y * WLs[C_DIM + c] + x.z * WLs[2 * C_DIM + c];
                Yt[cc * M_TILE + lm] = x.w;   // bank = lm%32, 2-way (free)
            }
        }
        __syncthreads();

        // register-blocked GEMM: 8m x 8j per thread
        #pragma unroll 8
        for (int cc = 0; cc < K_TILE; ++cc) {
            float4 ya = *(const float4*)&Yt[cc * M_TILE + mg * 8];
            float4 yb = *(const float4*)&Yt[cc * M_TILE + mg * 8 + 4];
            float w[8];
            #pragma unroll
            for (int ji = 0; ji < 8; ++ji) w[ji] = W1s[cc * H_DIM + jg + 16 * ji];
            float ym[8] = {ya.x, ya.y, ya.z, ya.w, yb.x, yb.y, yb.z, yb.w};
            #pragma unroll
            for (int mi = 0; mi < 8; ++mi)
                #pragma unroll
                for (int ji = 0; ji < 8; ++ji)
                    acc[mi][ji] = fmaf(ym[mi], w[ji], acc[mi][ji]);
        }
    }

    // reduce lin over the 2 loader threads of each node (adjacent lanes)
    lin += __shfl_xor(lin, 1);
    if (lq == 0) lin_lds[lm] = lin;

    // epilogue: relu + dot W2, partial per (m, jg)
    #pragma unroll
    for (int mi = 0; mi < 8; ++mi) {
        float s = 0.0f;
        #pragma unroll
        for (int ji = 0; ji < 8; ++ji) {
            float h = acc[mi][ji] + b1r[ji];
            h = h > 0.0f ? h : 0.0f;
            s = fmaf(h, W2r[ji], s);
        }
        nl_red[(mg * 8 + mi) * 17 + jg] = s;
    }
    __syncthreads();

    if (t < M_TILE) {
        float s = lin_lds[t];
        #pragma unroll
        for (int g = 0; g < 16; ++g) s += nl_red[t * 17 + g];
        s += b_lins[0] + b_lins[1] + b_lins[2] + b2[0];
        v_out[nbase + t] = s;
    }
}

// ---------------------------------------------------------------------------
// Kernel 2: per-segment aggregation (mean/max/min/quantiles) + final MLP
// ---------------------------------------------------------------------------
__global__ __launch_bounds__(256)
void aggregate_kernel(const float* __restrict__ v,
                      const int* __restrict__ batch,
                      const float* __restrict__ Wm1,
                      const float* __restrict__ bm1,
                      const float* __restrict__ Wm2,
                      const float* __restrict__ bm2,
                      float* __restrict__ out)
{
    __shared__ float vals[CAP];
    __shared__ float agg[12];
    __shared__ float red[8];

    const int b = blockIdx.x;
    const int t = threadIdx.x;
    const float FINF = __builtin_inff();

    // segment bounds via binary search (batch is sorted)
    int lo = 0, hi = N_NODES;
    while (lo < hi) { int mid = (lo + hi) >> 1; if (batch[mid] < b) lo = mid + 1; else hi = mid; }
    const int start = lo;
    hi = N_NODES;
    while (lo < hi) { int mid = (lo + hi) >> 1; if (batch[mid] < b + 1) lo = mid + 1; else hi = mid; }
    int cnt = lo - start;
    if (cnt > CAP) cnt = CAP;   // statistically impossible (mean 128, ~80 sigma)

    // load + local partial sum
    float lsum = 0.0f;
    for (int i = t; i < cnt; i += 256) {
        float x = v[start + i];
        vals[i] = x;
        lsum += x;
    }
    // pad to next pow2 with +inf
    int P = 1;
    while (P < cnt) P <<= 1;
    for (int i = cnt + t; i < P; i += 256) vals[i] = FINF;

    // block sum reduction
    #pragma unroll
    for (int o = 32; o > 0; o >>= 1) lsum += __shfl_down(lsum, o);
    if ((t & 63) == 0) red[t >> 6] = lsum;

    // bitonic sort ascending over P elements
    for (int k = 2; k <= P; k <<= 1) {
        for (int j = k >> 1; j > 0; j >>= 1) {
            __syncthreads();
            for (int i = t; i < P; i += 256) {
                int ixj = i ^ j;
                if (ixj > i) {
                    float a = vals[i], c = vals[ixj];
                    bool up = ((i & k) == 0);
                    if ((a > c) == up) { vals[i] = c; vals[ixj] = a; }
                }
            }
        }
    }
    __syncthreads();

    if (t == 0) {
        if (cnt > 0) {
            float total = red[0] + red[1] + red[2] + red[3];
            float cntf = (float)cnt;
            agg[0] = total / cntf;     // mean
            agg[1] = vals[cnt - 1];    // max
            agg[2] = vals[0];          // min
            #pragma unroll
            for (int i = 1; i <= 9; ++i) {
                float q = (float)i * 0.1f;
                float pos = q * (cntf - 1.0f);
                float f = floorf(pos);
                float frac = pos - f;
                int lo_i = (int)f;
                int hi_i = lo_i + 1;
                if (hi_i > cnt - 1) hi_i = cnt - 1;
                agg[2 + i] = vals[lo_i] + frac * (vals[hi_i] - vals[lo_i]);
            }
        } else {
            #pragma unroll
            for (int i = 0; i < 12; ++i) agg[i] = 0.0f;
        }
    }
    __syncthreads();

    // final MLP: relu(agg @ Wm1 + bm1) @ Wm2 + bm2
    float term = 0.0f;
    if (t < H_DIM) {
        float h = bm1[t];
        #pragma unroll
        for (int k = 0; k < 12; ++k) h = fmaf(agg[k], Wm1[k * H_DIM + t], h);
        h = h > 0.0f ? h : 0.0f;
        term = h * Wm2[t];
    }
    #pragma unroll
    for (int o = 32; o > 0; o >>= 1) term += __shfl_down(term, o);
    if ((t & 63) == 0) red[4 + (t >> 6)] = term;
    __syncthreads();
    if (t == 0) out[b] = red[4] + red[5] + red[6] + red[7] + bm2[0];
}

// ---------------------------------------------------------------------------
extern "C" void kernel_launch(void* const* d_in, const int* in_sizes, int n_in,
                              void* d_out, int out_size, void* d_ws, size_t ws_size,
                              hipStream_t stream)
{
    const float* emb    = (const float*)d_in[0];
    const int*   batch  = (const int*)d_in[1];
    const float* W_lins = (const float*)d_in[2];
    const float* b_lins = (const float*)d_in[3];
    const float* W1     = (const float*)d_in[4];
    const float* b1     = (const float*)d_in[5];
    const float* W2     = (const float*)d_in[6];
    const float* b2     = (const float*)d_in[7];
    const float* Wm1    = (const float*)d_in[8];
    const float* bm1    = (const float*)d_in[9];
    const float* Wm2    = (const float*)d_in[10];
    const float* bm2    = (const float*)d_in[11];

    float* out = (float*)d_out;
    float* v   = (float*)d_ws;   // 131072 floats = 512 KB scratch

    node_readout_kernel<<<N_NODES / M_TILE, 256, 0, stream>>>(
        emb, W_lins, b_lins, W1, b1, W2, b2, v);
    aggregate_kernel<<<B_SEG, 256, 0, stream>>>(
        v, batch, Wm1, bm1, Wm2, bm2, out);
}

// Round 2
// 501.182 us; speedup vs baseline: 1.0176x; 1.0176x over previous
//
#include <hip/hip_runtime.h>

#define N_NODES 131072
#define C_DIM   128
#define H_DIM   128
#define B_SEG   1024
#define M_TILE  128
#define K_TILE  32
#define YT_STR  132      // stride for Yt rows: mult of 4 (16B-aligned float4), %32==4 -> 4-way write conflict only
#define SEGCAP  384      // max plausible segment size (mean 128, sigma ~11; 384 is >20 sigma)

// ---------------------------------------------------------------------------
// Kernel 1: per-node readout  v[n] = lin(n) + relu(x3 @ W1 + b1) @ W2 + b2
// Loader: lane l reads float4 cc=l&31 of node p*8+(l>>5) -> 512B contiguous
// per half-wave. lin partials kept in 16 regs (one per pass), reduced by
// shfl_xor over the cc half at the end.
// ---------------------------------------------------------------------------
__global__ __launch_bounds__(256, 4)
void node_readout_kernel(const float* __restrict__ emb,
                         const float* __restrict__ W_lins,
                         const float* __restrict__ b_lins,
                         const float* __restrict__ W1,
                         const float* __restrict__ b1,
                         const float* __restrict__ W2,
                         const float* __restrict__ b2,
                         float* __restrict__ v_out)
{
    __shared__ float Yt[K_TILE * YT_STR];     // [cc][m] 16.9 KB
    __shared__ float W1s[K_TILE * H_DIM];     // 16 KB   (reused as nl_red in epilogue)
    __shared__ float WLs[3 * C_DIM];          // 1.5 KB
    __shared__ float lin_lds[M_TILE];         // 0.5 KB
    // total 34.8 KB -> 4 blocks/CU

    const int t  = threadIdx.x;
    const int nbase = blockIdx.x * M_TILE;
    const int ln = t >> 5;        // 0..7  : node sub-index within a pass
    const int cc = t & 31;        // float4 index within K-tile
    const int jg = t & 15;        // gemm j-group
    const int mg = t >> 4;        // gemm m-group

    for (int i = t; i < 3 * C_DIM; i += 256) WLs[i] = W_lins[i];

    float acc[8][8];
    #pragma unroll
    for (int mi = 0; mi < 8; ++mi)
        #pragma unroll
        for (int ji = 0; ji < 8; ++ji) acc[mi][ji] = 0.0f;

    float lin_p[16];
    #pragma unroll
    for (int p = 0; p < 16; ++p) lin_p[p] = 0.0f;

    // float4 view: node n starts at float4 index n*128
    const float4* xbase = (const float4*)emb + (size_t)(nbase + ln) * C_DIM;

    __syncthreads();   // WLs ready

    for (int ct = 0; ct < C_DIM / K_TILE; ++ct) {
        if (ct) __syncthreads();   // previous tile fully consumed

        // stage W1 K-tile: 32 x 128 = 16 KB, contiguous float4
        {
            const float4* src = (const float4*)(W1 + ct * K_TILE * H_DIM);
            float4* dst = (float4*)W1s;
            #pragma unroll
            for (int i = 0; i < 4; ++i) dst[t + 256 * i] = src[t + 256 * i];
        }
        // load X chunk: pass p covers nodes p*8..p*8+7; half-wave reads 512B contig
        {
            const int c0 = ct * K_TILE + cc;
            #pragma unroll
            for (int p = 0; p < 16; ++p) {
                float4 x = xbase[p * 8 * C_DIM + ct * K_TILE + cc];
                lin_p[p] += x.x * WLs[c0] + x.y * WLs[C_DIM + c0] + x.z * WLs[2 * C_DIM + c0];
                Yt[cc * YT_STR + p * 8 + ln] = x.w;
            }
        }
        __syncthreads();

        // register-blocked GEMM: 8m x 8j per thread
        #pragma unroll 8
        for (int k = 0; k < K_TILE; ++k) {
            float4 ya = *(const float4*)&Yt[k * YT_STR + mg * 8];
            float4 yb = *(const float4*)&Yt[k * YT_STR + mg * 8 + 4];
            float w[8];
            #pragma unroll
            for (int ji = 0; ji < 8; ++ji) w[ji] = W1s[k * H_DIM + jg + 16 * ji];
            float ym[8] = {ya.x, ya.y, ya.z, ya.w, yb.x, yb.y, yb.z, yb.w};
            #pragma unroll
            for (int mi = 0; mi < 8; ++mi)
                #pragma unroll
                for (int ji = 0; ji < 8; ++ji)
                    acc[mi][ji] = fmaf(ym[mi], w[ji], acc[mi][ji]);
        }
    }

    // reduce lin over the 32 cc lanes (lanes 0-31 / 32-63 of each wave)
    #pragma unroll
    for (int p = 0; p < 16; ++p) {
        float s = lin_p[p];
        s += __shfl_xor(s, 16);
        s += __shfl_xor(s, 8);
        s += __shfl_xor(s, 4);
        s += __shfl_xor(s, 2);
        s += __shfl_xor(s, 1);
        lin_p[p] = s;
    }
    if (cc == 0) {
        #pragma unroll
        for (int p = 0; p < 16; ++p) lin_lds[p * 8 + ln] = lin_p[p];
    }

    __syncthreads();                // all GEMM reads of W1s done -> reuse as nl_red
    float* nl_red = W1s;            // [m][jg] stride 17, 8.7 KB

    float b1r[8], W2r[8];
    #pragma unroll
    for (int ji = 0; ji < 8; ++ji) {
        int j = jg + 16 * ji;
        b1r[ji] = b1[j];
        W2r[ji] = W2[j];
    }

    #pragma unroll
    for (int mi = 0; mi < 8; ++mi) {
        float s = 0.0f;
        #pragma unroll
        for (int ji = 0; ji < 8; ++ji) {
            float h = acc[mi][ji] + b1r[ji];
            h = h > 0.0f ? h : 0.0f;
            s = fmaf(h, W2r[ji], s);
        }
        nl_red[(mg * 8 + mi) * 17 + jg] = s;
    }
    __syncthreads();

    if (t < M_TILE) {
        float s = lin_lds[t];
        #pragma unroll
        for (int g = 0; g < 16; ++g) s += nl_red[t * 17 + g];
        s += b_lins[0] + b_lins[1] + b_lins[2] + b2[0];
        v_out[nbase + t] = s;
    }
}

// ---------------------------------------------------------------------------
// Kernel 2: one wave per segment (4 waves/block). Rank-based sort (n^2 with
// broadcast LDS reads), quantiles, fused final MLP. 3 block barriers total.
// ---------------------------------------------------------------------------
__global__ __launch_bounds__(256)
void aggregate_kernel(const float* __restrict__ v,
                      const int* __restrict__ batch,
                      const float* __restrict__ Wm1,
                      const float* __restrict__ bm1,
                      const float* __restrict__ Wm2,
                      const float* __restrict__ bm2,
                      float* __restrict__ out)
{
    __shared__ float vals[4][SEGCAP];
    __shared__ float sorted[4][SEGCAP];
    __shared__ float agg_s[4][12];

    const int t    = threadIdx.x;
    const int wid  = t >> 6;
    const int lane = t & 63;
    const int b    = blockIdx.x * 4 + wid;

    // segment bounds via binary search (batch sorted ascending)
    int lo = 0, hi = N_NODES;
    while (lo < hi) { int mid = (lo + hi) >> 1; if (batch[mid] < b) lo = mid + 1; else hi = mid; }
    const int start = lo;
    hi = N_NODES;
    while (lo < hi) { int mid = (lo + hi) >> 1; if (batch[mid] <= b) lo = mid + 1; else hi = mid; }
    int cnt = lo - start;
    if (cnt > SEGCAP) cnt = SEGCAP;   // >20 sigma, never triggers

    // load + sum
    float lsum = 0.0f;
    for (int i = lane; i < cnt; i += 64) {
        float x = v[start + i];
        vals[wid][i] = x;
        lsum += x;
    }
    #pragma unroll
    for (int o = 32; o; o >>= 1) lsum += __shfl_xor(lsum, o);
    __syncthreads();

    // rank & scatter (stable tie-break matches lexsort)
    for (int i = lane; i < cnt; i += 64) {
        float xi = vals[wid][i];
        int r = 0;
        for (int j = 0; j < cnt; ++j) {
            float xj = vals[wid][j];   // broadcast read: j uniform across lanes
            r += (xj < xi) || (xj == xi && j < i);
        }
        sorted[wid][r] = xi;
    }
    __syncthreads();

    if (cnt > 0) {
        float cntf = (float)cnt;
        if (lane == 9)  agg_s[wid][0] = lsum / cntf;          // mean
        if (lane == 10) agg_s[wid][1] = sorted[wid][cnt - 1]; // max
        if (lane == 11) agg_s[wid][2] = sorted[wid][0];       // min
        if (lane < 9) {
            float q   = (float)(lane + 1) * 0.1f;
            float pos = q * (cntf - 1.0f);
            float f   = floorf(pos);
            float frac = pos - f;
            int loi = (int)f;
            int hii = loi + 1; if (hii > cnt - 1) hii = cnt - 1;
            agg_s[wid][3 + lane] = sorted[wid][loi] + frac * (sorted[wid][hii] - sorted[wid][loi]);
        }
    } else {
        if (lane < 12) agg_s[wid][lane] = 0.0f;
    }
    __syncthreads();

    // final MLP: relu(agg @ Wm1 + bm1) @ Wm2 + bm2
    float term = 0.0f;
    #pragma unroll
    for (int rj = 0; rj < 2; ++rj) {
        int j = lane + 64 * rj;
        float h = bm1[j];
        #pragma unroll
        for (int k = 0; k < 12; ++k) h = fmaf(agg_s[wid][k], Wm1[k * H_DIM + j], h);
        h = h > 0.0f ? h : 0.0f;
        term = fmaf(h, Wm2[j], term);
    }
    #pragma unroll
    for (int o = 32; o; o >>= 1) term += __shfl_xor(term, o);
    if (lane == 0) out[b] = term + bm2[0];
}

// ---------------------------------------------------------------------------
extern "C" void kernel_launch(void* const* d_in, const int* in_sizes, int n_in,
                              void* d_out, int out_size, void* d_ws, size_t ws_size,
                              hipStream_t stream)
{
    const float* emb    = (const float*)d_in[0];
    const int*   batch  = (const int*)d_in[1];
    const float* W_lins = (const float*)d_in[2];
    const float* b_lins = (const float*)d_in[3];
    const float* W1     = (const float*)d_in[4];
    const float* b1     = (const float*)d_in[5];
    const float* W2     = (const float*)d_in[6];
    const float* b2     = (const float*)d_in[7];
    const float* Wm1    = (const float*)d_in[8];
    const float* bm1    = (const float*)d_in[9];
    const float* Wm2    = (const float*)d_in[10];
    const float* bm2    = (const float*)d_in[11];

    float* out = (float*)d_out;
    float* vbuf = (float*)d_ws;   // 131072 floats = 512 KB scratch

    node_readout_kernel<<<N_NODES / M_TILE, 256, 0, stream>>>(
        emb, W_lins, b_lins, W1, b1, W2, b2, vbuf);
    aggregate_kernel<<<B_SEG / 4, 256, 0, stream>>>(
        vbuf, batch, Wm1, bm1, Wm2, bm2, out);
}